// Round 4
// baseline (163.461 us; speedup 1.0000x reference)
//
#include <hip/hip_runtime.h>

// MultiHeadSelfAttention: N=8, C=512, heads=8, d=64, S=1024 (32x32), fp32 in/out.
// R4: 3 kernels total. qkv reads raw x/W (in-staging transpose+cast, dbuf);
// attn computes O^T in PV (8B stores, shuffle-broadcast 1/l); out_gemm dbuf
// with in-staging Wo cast. prep deleted.

typedef _Float16 f16x8 __attribute__((ext_vector_type(8)));
typedef _Float16 f16x4 __attribute__((ext_vector_type(4)));
typedef _Float16 f16x2 __attribute__((ext_vector_type(2)));
typedef float f32x4 __attribute__((ext_vector_type(4)));

__device__ inline void gl_lds16(const void* g, void* l) {
  __builtin_amdgcn_global_load_lds((const __attribute__((address_space(1))) void*)g,
                                   (__attribute__((address_space(3))) void*)l, 16, 0, 0);
}

__device__ inline float fexp2(float x) {
#if __has_builtin(__builtin_amdgcn_exp2f)
  return __builtin_amdgcn_exp2f(x);
#else
  return exp2f(x);
#endif
}

// ---------------- QKV GEMM: (8192x512)*(1536x512)^T + bias -------------------
// Reads raw fp32 x (N,C,S) and Wq/Wk/Wv; stages with in-kernel transpose/cast.
// Q,K -> QK[m][0..1023] fp16 (Q pre-scaled by log2e/8); V -> Vt[(n8h)][d][p],
// s-permuted: within each 32-block, p = q*8 + t*4 + r holds s_local = 16t+4q+r.
__global__ __launch_bounds__(256, 2) void qkv_gemm(
    const float* __restrict__ x,
    const float* __restrict__ Wq, const float* __restrict__ Wk,
    const float* __restrict__ Wv,
    const float* __restrict__ bq, const float* __restrict__ bk,
    const float* __restrict__ bv,
    _Float16* __restrict__ QK, _Float16* __restrict__ Vt) {
  __shared__ _Float16 smem[16896];  // [A0 4k][B0 4k][A1 4k][B1 4k]; epi: 128x132
  const int tid = threadIdx.x;
  const int lane = tid & 63, w = tid >> 6;
  const int quad = lane >> 4, l15 = lane & 15;
  const int bn = blockIdx.x * 128, bm = blockIdx.y * 128;
  const int wr = (w >> 1) * 64, wc = (w & 1) * 64;
  const int n = bm >> 10, s_base = bm & 1023;
  const float g = 0.18033688011112042f;  // log2(e)/8
  const float* Wsel = (bn < 512) ? Wq : (bn < 1024 ? Wk : Wv);
  const float* bsel = (bn < 512) ? bq : (bn < 1024 ? bk : bv);
  const int row0 = bn & 511;
  const float gw = (bn < 512) ? g : 1.0f;

  // staging maps
  const int cpr = (tid >> 4) * 2;       // c-pair 0,2..30 (within k-tile)
  const int s8 = (tid & 15) * 8;        // s-chunk base 0..120
  const int wrow = tid >> 1;            // W row 0..127
  const int wh = (tid & 1) * 16;        // k-half 0 / 16

  float av[16], wv16[16];
  f32x4 acc[4][4] = {};

  // prologue: load k-tile 0
  {
    const float* xs = x + ((size_t)(n * 512 + cpr) * 1024) + s_base + s8;
    *(float4*)(av + 0) = *(const float4*)(xs);
    *(float4*)(av + 4) = *(const float4*)(xs + 4);
    *(float4*)(av + 8) = *(const float4*)(xs + 1024);
    *(float4*)(av + 12) = *(const float4*)(xs + 1028);
    const float* ws = Wsel + (size_t)(row0 + wrow) * 512 + wh;
    *(float4*)(wv16 + 0) = *(const float4*)(ws);
    *(float4*)(wv16 + 4) = *(const float4*)(ws + 4);
    *(float4*)(wv16 + 8) = *(const float4*)(ws + 8);
    *(float4*)(wv16 + 12) = *(const float4*)(ws + 12);
  }
  for (int ki = 0; ki < 16; ++ki) {
    const int buf = ki & 1;
    _Float16* As = smem + buf * 8192;
    _Float16* Bs = smem + buf * 8192 + 4096;
    // write staged regs (tile ki) into buf
#pragma unroll
    for (int i = 0; i < 8; ++i) {
      int s_l = s8 + i;
      int slot = (cpr >> 3) ^ ((s_l >> 1) & 3);
      f16x2 pk = {(_Float16)av[i], (_Float16)av[8 + i]};
      *(f16x2*)(As + s_l * 32 + slot * 8 + (cpr & 7)) = pk;
    }
#pragma unroll
    for (int c = 0; c < 2; ++c) {
      int jc = (tid & 1) * 2 + c;
      int slot = jc ^ ((wrow >> 1) & 3);
      f16x8 pk;
#pragma unroll
      for (int j = 0; j < 8; ++j) pk[j] = (_Float16)(wv16[c * 8 + j] * gw);
      *(f16x8*)(Bs + wrow * 32 + slot * 8) = pk;
    }
    __syncthreads();
    // prefetch tile ki+1 into regs
    if (ki < 15) {
      int k0 = (ki + 1) * 32;
      const float* xs = x + ((size_t)(n * 512 + k0 + cpr) * 1024) + s_base + s8;
      *(float4*)(av + 0) = *(const float4*)(xs);
      *(float4*)(av + 4) = *(const float4*)(xs + 4);
      *(float4*)(av + 8) = *(const float4*)(xs + 1024);
      *(float4*)(av + 12) = *(const float4*)(xs + 1028);
      const float* ws = Wsel + (size_t)(row0 + wrow) * 512 + k0 + wh;
      *(float4*)(wv16 + 0) = *(const float4*)(ws);
      *(float4*)(wv16 + 4) = *(const float4*)(ws + 4);
      *(float4*)(wv16 + 8) = *(const float4*)(ws + 8);
      *(float4*)(wv16 + 12) = *(const float4*)(ws + 12);
    }
    f16x8 af[4], bf[4];
#pragma unroll
    for (int i = 0; i < 4; ++i) {
      int ra = wr + i * 16 + l15;
      af[i] = *(const f16x8*)(As + ra * 32 + (quad ^ ((ra >> 1) & 3)) * 8);
      int rb = wc + i * 16 + l15;
      bf[i] = *(const f16x8*)(Bs + rb * 32 + (quad ^ ((rb >> 1) & 3)) * 8);
    }
#pragma unroll
    for (int i = 0; i < 4; ++i)
#pragma unroll
      for (int j = 0; j < 4; ++j)
        acc[i][j] = __builtin_amdgcn_mfma_f32_16x16x32_f16(af[i], bf[j], acc[i][j], 0, 0, 0);
    __syncthreads();
  }
  if (bn < 1024) {
    // Q/K blocks: direct store
#pragma unroll
    for (int j = 0; j < 4; ++j) {
      int cl = wc + j * 16 + l15;
      float bb = bsel[(bn & 511) + cl] * gw;
      int col = bn + cl;
#pragma unroll
      for (int i = 0; i < 4; ++i) {
        int rowb = bm + wr + i * 16 + quad * 4;
#pragma unroll
        for (int r = 0; r < 4; ++r)
          QK[(size_t)(rowb + r) * 1024 + col] = (_Float16)(acc[i][j][r] + bb);
      }
    }
  } else {
    // V blocks: transpose tile through LDS, store coalesced with s-permutation
    __syncthreads();
#pragma unroll
    for (int j = 0; j < 4; ++j) {
      int cl = wc + j * 16 + l15;
      float bb = bsel[cl + (bn & 511)];
#pragma unroll
      for (int i = 0; i < 4; ++i) {
        int row = wr + i * 16 + quad * 4;
        f16x4 pk;
#pragma unroll
        for (int r = 0; r < 4; ++r) pk[r] = (_Float16)(acc[i][j][r] + bb);
        *(f16x4*)(smem + cl * 132 + row) = pk;
      }
    }
    __syncthreads();
    const int s0g = bm & 1023;
    const int vh = (bn - 1024) >> 6;
    const int cl = tid >> 1, par = tid & 1;
    const int hh = vh + (cl >> 6), d = cl & 63;
    const size_t vrow = (((size_t)((n * 8 + hh) * 64 + d)) << 10) + s0g;
#pragma unroll
    for (int gq = 0; gq < 8; ++gq) {
      int pb = gq * 16 + par * 8;
      int a32 = pb & ~31, q = (pb >> 3) & 3;
      f16x4 lo = *(const f16x4*)(smem + cl * 132 + a32 + 4 * q);
      f16x4 hi = *(const f16x4*)(smem + cl * 132 + a32 + 16 + 4 * q);
      f16x8 o = {lo[0], lo[1], lo[2], lo[3], hi[0], hi[1], hi[2], hi[3]};
      *(f16x8*)(Vt + vrow + pb) = o;
    }
  }
}

// ---------------- flash attention: O^T PV orientation -------------------------
// 256 thr (4 waves), 32 q-rows/wave, grid (8 q-tiles, 64 n*h). LDS 48 KB.
__global__ __launch_bounds__(256, 2) void attn(
    const _Float16* __restrict__ QK, const _Float16* __restrict__ Vt,
    _Float16* __restrict__ O16) {
  __shared__ _Float16 Qs[128 * 64];
  __shared__ _Float16 Ks[128 * 64];
  __shared__ _Float16 Vs[64 * 128];
  const int tid = threadIdx.x, lane = tid & 63, w = tid >> 6;
  const int quad = lane >> 4, l15 = lane & 15;
  const int n = blockIdx.y >> 3, h = blockIdx.y & 7;
  const int q0 = blockIdx.x * 128;
#pragma unroll
  for (int c = 0; c < 4; ++c) {
    int idx = c * 256 + tid;
    int row = idx >> 3, sc = idx & 7;
    int dg = sc ^ (row & 7);
    gl_lds16(QK + (size_t)(n * 1024 + q0 + row) * 1024 + h * 64 + dg * 8, Qs + idx * 8);
  }
  __syncthreads();
  f16x8 qf[2][2];
#pragma unroll
  for (int mt = 0; mt < 2; ++mt)
#pragma unroll
    for (int dc = 0; dc < 2; ++dc) {
      int row = w * 32 + mt * 16 + l15;
      qf[mt][dc] = *(const f16x8*)(Qs + row * 64 + ((dc * 4 + quad) ^ (row & 7)) * 8);
    }
  f32x4 oaccT[4][2] = {};  // [nt d-tile][mt q-tile], rows=d cols=q
  f32x4 lsum[2] = {};
  const f16x8 ones = {(_Float16)1, (_Float16)1, (_Float16)1, (_Float16)1,
                      (_Float16)1, (_Float16)1, (_Float16)1, (_Float16)1};

  for (int kt = 0; kt < 8; ++kt) {
    __syncthreads();
#pragma unroll
    for (int c = 0; c < 4; ++c) {
      int idx = c * 256 + tid;
      int row = idx >> 3, sck = idx & 7;
      int dg = sck ^ (row & 7);
      gl_lds16(QK + (size_t)(n * 1024 + kt * 128 + row) * 1024 + 512 + h * 64 + dg * 8,
               Ks + idx * 8);
      int d = idx >> 4, scv = idx & 15;
      int vg = scv ^ (d & 7);
      gl_lds16(Vt + (size_t)((n * 8 + h) * 64 + d) * 1024 + kt * 128 + vg * 8,
               Vs + idx * 8);
    }
    __syncthreads();
#pragma unroll
    for (int sc = 0; sc < 4; ++sc) {
      f32x4 sacc[2][2] = {};
#pragma unroll
      for (int t = 0; t < 2; ++t) {
        int rk = (sc * 2 + t) * 16 + l15;
        f16x8 kf0 = *(const f16x8*)(Ks + rk * 64 + ((quad) ^ (rk & 7)) * 8);
        f16x8 kf1 = *(const f16x8*)(Ks + rk * 64 + ((4 + quad) ^ (rk & 7)) * 8);
#pragma unroll
        for (int mt = 0; mt < 2; ++mt) {
          sacc[mt][t] = __builtin_amdgcn_mfma_f32_16x16x32_f16(kf0, qf[mt][0], sacc[mt][t], 0, 0, 0);
          sacc[mt][t] = __builtin_amdgcn_mfma_f32_16x16x32_f16(kf1, qf[mt][1], sacc[mt][t], 0, 0, 0);
        }
      }
      f16x8 pf[2];
#pragma unroll
      for (int mt = 0; mt < 2; ++mt) {
#pragma unroll
        for (int t = 0; t < 2; ++t)
#pragma unroll
          for (int r = 0; r < 4; ++r)
            pf[mt][t * 4 + r] = (_Float16)fexp2(sacc[mt][t][r]);
        lsum[mt] = __builtin_amdgcn_mfma_f32_16x16x32_f16(pf[mt], ones, lsum[mt], 0, 0, 0);
      }
#pragma unroll
      for (int nt = 0; nt < 4; ++nt) {
        int rd = nt * 16 + l15;
        f16x8 vf = *(const f16x8*)(Vs + rd * 128 + ((sc * 4 + quad) ^ (rd & 7)) * 8);
#pragma unroll
        for (int mt = 0; mt < 2; ++mt)
          oaccT[nt][mt] = __builtin_amdgcn_mfma_f32_16x16x32_f16(vf, pf[mt], oaccT[nt][mt], 0, 0, 0);
      }
    }
  }
  // epilogue: O^T layout — lane owns q = q0 + w*32 + mt*16 + l15, d = nt*16+quad*4+r.
  // 1/l broadcast: lsum C-layout has l(q=quad*4+r) -> pre-place reg (l15&3), shuffle.
#pragma unroll
  for (int mt = 0; mt < 2; ++mt) {
    int r3 = l15 & 3;
    float lv = lsum[mt][0];
    lv = (r3 == 1) ? lsum[mt][1] : lv;
    lv = (r3 == 2) ? lsum[mt][2] : lv;
    lv = (r3 == 3) ? lsum[mt][3] : lv;
    float lq = __shfl(lv, (l15 >> 2) * 16 + (l15 & 3), 64);
    float rinv = 1.0f / lq;
    int q = q0 + w * 32 + mt * 16 + l15;
    int i = h * 128 + (q >> 3);
    size_t base = (size_t)(n * 1024 + i) * 512 + (q & 7) * 64 + quad * 4;
#pragma unroll
    for (int nt = 0; nt < 4; ++nt) {
      f16x4 pk;
#pragma unroll
      for (int r = 0; r < 4; ++r) pk[r] = (_Float16)(oaccT[nt][mt][r] * rinv);
      *(f16x4*)(O16 + base + nt * 16) = pk;
    }
  }
}

// ---------------- out GEMM: (8192x512)*(512x512)^T + bo -> fp32 out ----------
// A = O16 fp16 via gl_lds16 (dbuf); B = raw fp32 Wo cast in-staging (dbuf).
__global__ __launch_bounds__(256, 2) void out_gemm(
    const _Float16* __restrict__ A, const float* __restrict__ Wo,
    const float* __restrict__ bo, float* __restrict__ out) {
  __shared__ _Float16 smem[16384];  // [A0 4k][B0 4k][A1 4k][B1 4k]
  const int tid = threadIdx.x;
  const int lane = tid & 63, w = tid >> 6;
  const int quad = lane >> 4, l15 = lane & 15;
  const int bm = blockIdx.x * 128, bn = blockIdx.y * 128;
  const int wr = (w >> 1) * 64, wc = (w & 1) * 64;
  const int wrow = tid >> 1, wh = (tid & 1) * 16;
  float wv16[16];
  f32x4 acc[4][4] = {};
  // prologue: A tile0 via gl_lds16 into buf0; W tile0 into regs
  {
#pragma unroll
    for (int c = 0; c < 2; ++c) {
      int idx = c * 256 + tid;
      int row = idx >> 2, sc = idx & 3;
      int kg = sc ^ ((row >> 1) & 3);
      gl_lds16(A + (size_t)(bm + row) * 512 + kg * 8, smem + idx * 8);
    }
    const float* ws = Wo + (size_t)(bn + wrow) * 512 + wh;
    *(float4*)(wv16 + 0) = *(const float4*)(ws);
    *(float4*)(wv16 + 4) = *(const float4*)(ws + 4);
    *(float4*)(wv16 + 8) = *(const float4*)(ws + 8);
    *(float4*)(wv16 + 12) = *(const float4*)(ws + 12);
  }
  for (int ki = 0; ki < 16; ++ki) {
    const int buf = ki & 1;
    _Float16* As = smem + buf * 8192;
    _Float16* Bs = smem + buf * 8192 + 4096;
#pragma unroll
    for (int c = 0; c < 2; ++c) {
      int jc = (tid & 1) * 2 + c;
      int slot = jc ^ ((wrow >> 1) & 3);
      f16x8 pk;
#pragma unroll
      for (int j = 0; j < 8; ++j) pk[j] = (_Float16)wv16[c * 8 + j];
      *(f16x8*)(Bs + wrow * 32 + slot * 8) = pk;
    }
    __syncthreads();
    if (ki < 15) {
      int k0 = (ki + 1) * 32;
      _Float16* Asn = smem + (1 - buf) * 8192;
#pragma unroll
      for (int c = 0; c < 2; ++c) {
        int idx = c * 256 + tid;
        int row = idx >> 2, sc = idx & 3;
        int kg = sc ^ ((row >> 1) & 3);
        gl_lds16(A + (size_t)(bm + row) * 512 + k0 + kg * 8, Asn + idx * 8);
      }
      const float* ws = Wo + (size_t)(bn + wrow) * 512 + k0 + wh;
      *(float4*)(wv16 + 0) = *(const float4*)(ws);
      *(float4*)(wv16 + 4) = *(const float4*)(ws + 4);
      *(float4*)(wv16 + 8) = *(const float4*)(ws + 8);
      *(float4*)(wv16 + 12) = *(const float4*)(ws + 12);
    }
    f16x8 af[4], bf[4];
#pragma unroll
    for (int i = 0; i < 4; ++i) {
      int ra = wr + i * 16 + l15;
      af[i] = *(const f16x8*)(As + ra * 32 + (quad ^ ((ra >> 1) & 3)) * 8);
      int rb = wc + i * 16 + l15;
      bf[i] = *(const f16x8*)(Bs + rb * 32 + (quad ^ ((rb >> 1) & 3)) * 8);
    }
#pragma unroll
    for (int i = 0; i < 4; ++i)
#pragma unroll
      for (int j = 0; j < 4; ++j)
        acc[i][j] = __builtin_amdgcn_mfma_f32_16x16x32_f16(af[i], bf[j], acc[i][j], 0, 0, 0);
    __syncthreads();
  }
#pragma unroll
  for (int j = 0; j < 4; ++j) {
    int col = bn + wc + j * 16 + l15;
    float bb = bo[col];
#pragma unroll
    for (int i = 0; i < 4; ++i) {
      int rowb = bm + wr + i * 16 + quad * 4;
#pragma unroll
      for (int r = 0; r < 4; ++r)
        out[(size_t)(rowb + r) * 512 + col] = acc[i][j][r] + bb;
    }
  }
}

extern "C" void kernel_launch(void* const* d_in, const int* in_sizes, int n_in,
                              void* d_out, int out_size, void* d_ws, size_t ws_size,
                              hipStream_t stream) {
  const float* x  = (const float*)d_in[0];
  const float* Wq = (const float*)d_in[1];
  const float* bq = (const float*)d_in[2];
  const float* Wk = (const float*)d_in[3];
  const float* bk = (const float*)d_in[4];
  const float* Wv = (const float*)d_in[5];
  const float* bv = (const float*)d_in[6];
  const float* Wo = (const float*)d_in[7];
  const float* bo = (const float*)d_in[8];
  float* out = (float*)d_out;
  char* ws = (char*)d_ws;

  _Float16* QK  = (_Float16*)(ws);               // 16 MB
  _Float16* Vt  = (_Float16*)(ws + (16u << 20)); // 8 MB
  _Float16* O16 = (_Float16*)(ws + (24u << 20)); // 8 MB

  hipLaunchKernelGGL(qkv_gemm, dim3(12, 64), dim3(256), 0, stream,
                     x, Wq, Wk, Wv, bq, bk, bv, QK, Vt);
  hipLaunchKernelGGL(attn, dim3(8, 64), dim3(256), 0, stream, QK, Vt, O16);
  hipLaunchKernelGGL(out_gemm, dim3(64, 4), dim3(256), 0, stream,
                     O16, Wo, bo, out);
}